// Round 5
// baseline (243.428 us; speedup 1.0000x reference)
//
#include <hip/hip_runtime.h>
#include <math.h>

#define IMH 480
#define IMW 640
#define HW (IMH*IMW)
#define KPT 512
#define DESC 256
#define CAP 12288
#define NMSR 3

// ---------------------------------------------------------------- BAD offsets at COMPILE TIME
// np.random.RandomState(42).uniform(-8,8,(256,4)) -> np.round (half-to-even) -> int.
struct OffsTable { int v[1024]; };

constexpr unsigned mt_temper(unsigned y) {
  y ^= (y >> 11);
  y ^= (y << 7)  & 0x9d2c5680u;
  y ^= (y << 15) & 0xefc60000u;
  y ^= (y >> 18);
  return y;
}

constexpr OffsTable make_offs() {
  OffsTable T{};
  unsigned mt[624]{};
  unsigned s = 42u;
  for (int i = 0; i < 624; ++i) { mt[i] = s; s = 1812433253u * (s ^ (s >> 30)) + (unsigned)i + 1u; }
  int mti = 624;
  unsigned draws[2048]{};
  for (int i = 0; i < 2048; ++i) {
    if (mti >= 624) {
      for (int k = 0; k < 624; ++k) {
        unsigned y = (mt[k] & 0x80000000u) | (mt[(k + 1) % 624] & 0x7fffffffu);
        unsigned v = mt[(k + 397) % 624] ^ (y >> 1);
        if (y & 1u) v ^= 0x9908b0dfu;
        mt[k] = v;
      }
      mti = 0;
    }
    draws[i] = mt_temper(mt[mti++]);
  }
  for (int i = 0; i < 1024; ++i) {
    unsigned a = draws[2 * i] >> 5, b = draws[2 * i + 1] >> 6;
    double r = ((double)a * 67108864.0 + (double)b) / 9007199254740992.0;
    double val = -8.0 + 16.0 * r;
    double f = (double)(long long)val;
    if (val < f) f -= 1.0;                 // floor
    double diff = val - f;
    double rounded;
    if (diff > 0.5) rounded = f + 1.0;
    else if (diff < 0.5) rounded = f;
    else { long long fi = (long long)f; rounded = (fi % 2 == 0) ? f : f + 1.0; }  // half->even
    T.v[i] = (int)rounded;
  }
  return T;
}

__constant__ OffsTable OFFS_TAB = make_offs();

// ---------------------------------------------------------------- init
__global__ void init_misc_kernel(int* __restrict__ counts, float* __restrict__ sel_val,
                                 int* __restrict__ sel_idx,
                                 float* __restrict__ cs0, float* __restrict__ cs1,
                                 float* __restrict__ cs2,
                                 int* __restrict__ rank_arr, int* __restrict__ done,
                                 float* __restrict__ K) {
  int t = blockIdx.x * blockDim.x + threadIdx.x;
  if (t < 2) counts[t] = 0;
  if (t < 2 * KPT) { sel_val[t] = 0.f; sel_idx[t] = -1; }
  if (t < 128) done[t] = 0;                // last-block tickets for rank->scatter
  if (t < 513) {
    // triple-buffer colsum rotation: iteration t reads cs[(t+2)%3], atomically
    // accumulates cs[t%3], zeros cs[(t+1)%3]. Seed the first read buffer (cs2)
    // with nu so b0 = nu/cs2 = 1 (v=0 initial), zero the first write buffer.
    cs0[t] = 0.f;
    cs1[t] = 0.f;
    cs2[t] = (t == KPT) ? 0.5f : (1.0f / 1024.0f);
    // dustbin row/col of the linear-domain kernel matrix: exp(UNUSED/EPS)=exp(1)
    float e = expf(1.0f);
    K[(size_t)KPT * 513 + t] = e;
    K[(size_t)t * 513 + KPT] = e;
  }
  for (int i = t; i < 2 * CAP; i += 16384) rank_arr[i] = 0;
}

// ---------------------------------------------------------------- fused detector + NMS
#define FTW 64
#define FTH 8
__global__ void det_nms_kernel(const float* __restrict__ img0, const float* __restrict__ img1,
                               float* __restrict__ smooth,
                               float* __restrict__ cand_val, int* __restrict__ cand_idx,
                               int* __restrict__ counts) {
  const int b = blockIdx.z;
  const int x0 = blockIdx.x * FTW;
  const int y0 = blockIdx.y * FTH;
  const float* __restrict__ img = b ? img1 : img0;
  __shared__ float im[(FTH + 10) * (FTW + 10)];   // 18 x 74 image stage (0 OOB)
  __shared__ float scs[(FTH + 6) * (FTW + 6)];    // 14 x 70 scores (-inf OOB)
  __shared__ float hm[(FTH + 6) * FTW];           // 14 x 64 horizontal 7-max
  __shared__ float lval[128];
  __shared__ int lidx[128];
  __shared__ int lcnt, gbase;
  const int tid = threadIdx.x;
  if (tid == 0) lcnt = 0;
  for (int i = tid; i < 18 * 74; i += 256) {
    int ly = i / 74, lx = i - ly * 74;
    int gy = y0 + ly - 5, gx = x0 + lx - 5;
    im[i] = (gy >= 0 && gy < IMH && gx >= 0 && gx < IMW) ? img[gy * IMW + gx] : 0.f;
  }
  __syncthreads();
  for (int i = tid; i < 14 * 70; i += 256) {
    int ly = i / 70, lx = i - ly * 70;
    int gy = y0 + ly - 3, gx = x0 + lx - 3;
    float sc;
    if (gy < 0 || gy >= IMH || gx < 0 || gx >= IMW) {
      sc = -INFINITY;                 // reference NMS pads with -inf
    } else {
      float a[5][5];
      #pragma unroll
      for (int ii = 0; ii < 5; ++ii)
        #pragma unroll
        for (int jj = 0; jj < 5; ++jj)
          a[ii][jj] = im[(ly + ii) * 74 + lx + jj];
      float sm = 0.f;
      #pragma unroll
      for (int ii = 0; ii < 5; ++ii)
        #pragma unroll
        for (int jj = 0; jj < 5; ++jj) sm += a[ii][jj];
      if (ly >= 3 && ly < 3 + FTH && lx >= 3 && lx < 3 + FTW)
        smooth[b * HW + gy * IMW + gx] = sm * (1.f / 25.f);
      float sxx = 0.f, syy = 0.f, sxy = 0.f;
      #pragma unroll
      for (int cy = -1; cy <= 1; ++cy) {
        #pragma unroll
        for (int cx = -1; cx <= 1; ++cx) {
          int yy = gy + cy, xx = gx + cx;
          if (yy < 0 || yy >= IMH || xx < 0 || xx >= IMW) continue;  // zero-pad box conv
          int iu = cy + 2, iv = cx + 2;
          float ix = (a[iu - 1][iv + 1] - a[iu - 1][iv - 1])
                   + 2.f * (a[iu][iv + 1] - a[iu][iv - 1])
                   + (a[iu + 1][iv + 1] - a[iu + 1][iv - 1]);
          float iy = (a[iu + 1][iv - 1] + 2.f * a[iu + 1][iv] + a[iu + 1][iv + 1])
                   - (a[iu - 1][iv - 1] + 2.f * a[iu - 1][iv] + a[iu - 1][iv + 1]);
          sxx += ix * ix; syy += iy * iy; sxy += ix * iy;
        }
      }
      sxx *= (1.f / 9.f); syy *= (1.f / 9.f); sxy *= (1.f / 9.f);
      float half_tr = 0.5f * (sxx + syy);
      float hd = 0.5f * (sxx - syy);
      sc = half_tr - sqrtf(hd * hd + sxy * sxy + 1e-12f);
    }
    scs[i] = sc;
  }
  __syncthreads();
  for (int i = tid; i < 14 * 64; i += 256) {
    int ly = i / 64, lx = i - ly * 64;
    const float* r = scs + ly * 70 + lx;
    float m = r[0];
    #pragma unroll
    for (int d = 1; d < 7; ++d) m = fmaxf(m, r[d]);
    hm[i] = m;
  }
  __syncthreads();
  for (int i = tid; i < FTH * FTW; i += 256) {
    int ly = i >> 6, lx = i & 63;
    float s = scs[(ly + 3) * 70 + lx + 3];
    if (s > 0.f) {
      float m = hm[ly * 64 + lx];
      #pragma unroll
      for (int d = 1; d < 7; ++d) m = fmaxf(m, hm[(ly + d) * 64 + lx]);
      if (s >= m - 1e-7f) {
        int slot = atomicAdd(&lcnt, 1);
        if (slot < 128) { lval[slot] = s; lidx[slot] = (y0 + ly) * IMW + (x0 + lx); }
      }
    }
  }
  __syncthreads();
  if (tid == 0) gbase = atomicAdd(&counts[b], min(lcnt, 128));
  __syncthreads();
  int nc = min(lcnt, 128);
  for (int i = tid; i < nc; i += 256) {
    int slot = gbase + i;
    if (slot < CAP) {
      cand_val[b * CAP + slot] = lval[i];
      cand_idx[b * CAP + slot] = lidx[i];
    }
  }
}

// ---------------------------------------------------------------- top-512: 2D-tiled rank count
// Scatter is FUSED into the tail via the last-done-block pattern: every
// active block fences its rank adds and takes a ticket; the block seeing
// ticket == NJ-1 for its row-stripe re-reads the now-final ranks with
// device-scope atomic reads (atomicAdd(p,0) — coherent across XCD L2s,
// unlike plain loads) and writes sel_val/sel_idx. Deterministic: same adds,
// same final ranks, same writes as the separate scatter dispatch.
__global__ void rank_partial_kernel(const float* __restrict__ cand_val,
                                    const int* __restrict__ cand_idx,
                                    const int* __restrict__ counts,
                                    int* __restrict__ rank_arr,
                                    int* __restrict__ done,
                                    float* __restrict__ sel_val, int* __restrict__ sel_idx) {
  int b = blockIdx.z;
  int n = counts[b]; if (n > CAP) n = CAP;
  if ((int)(blockIdx.x * 256) >= n || (int)(blockIdx.y * 256) >= n) return;
  const float* cv = cand_val + b * CAP;
  const int* ci = cand_idx + b * CAP;
  int i = blockIdx.x * 256 + threadIdx.x;
  int j = blockIdx.y * 256 + threadIdx.x;
  __shared__ unsigned long long sk[256];
  __shared__ int is_last;
  sk[threadIdx.x] = (j < n)
      ? (((unsigned long long)__float_as_uint(cv[j]) << 32) | (0xFFFFFFFFu - (unsigned)ci[j]))
      : 0ull;
  __syncthreads();
  unsigned long long ki = 0ull;
  if (i < n) {
    ki = ((unsigned long long)__float_as_uint(cv[i]) << 32)
       | (0xFFFFFFFFu - (unsigned)ci[i]);
    int r = 0;
    #pragma unroll 8
    for (int t = 0; t < 256; ++t) r += (sk[t] > ki) ? 1 : 0;
    atomicAdd(&rank_arr[b * CAP + i], r);
  }
  __threadfence();
  __syncthreads();
  if (threadIdx.x == 0) {
    int NJ = (n + 255) >> 8;                       // active j-blocks for this image
    int t = atomicAdd(&done[b * 64 + blockIdx.x], 1);
    is_last = (t == NJ - 1) ? 1 : 0;
  }
  __syncthreads();
  if (is_last && i < n) {
    int r = atomicAdd(&rank_arr[b * CAP + i], 0);  // device-scope coherent read
    if (r < KPT) {
      sel_val[b * KPT + r] = __uint_as_float((unsigned)(ki >> 32));
      sel_idx[b * KPT + r] = (int)(0xFFFFFFFFu - (unsigned)ki);
    }
  }
}

// ---------------------------------------------------------------- kp out + BAD desc + L2 norm
// 1024 blocks x 1 wave: one wave per keypoint. The random gather into smooth
// is latency-bound; maximal wave count is the right shape (R3's 4-wave fused
// variant concentrated 1024 gathers into 384 imbalanced waves -> +9 us).
__global__ void kp_desc_kernel(const float* __restrict__ sel_val, const int* __restrict__ sel_idx,
                               const float* __restrict__ smooth,
                               float* __restrict__ desc, float* __restrict__ a2_out,
                               float* __restrict__ out) {
  int blk = blockIdx.x;
  int b = blk >> 9;
  int k = blk & 511;
  int lane = threadIdx.x;
  float val = sel_val[b * KPT + k];
  int idx = sel_idx[b * KPT + k];
  bool valid = (val > 0.f) && (idx >= 0);
  int y = 0, x = 0;
  if (valid) { y = idx / IMW; x = idx - y * IMW; }
  const float* sm = smooth + b * HW;
  float d[4];
  #pragma unroll
  for (int t2 = 0; t2 < 4; ++t2) {
    int pp = (lane << 2) + t2;
    int oy1 = OFFS_TAB.v[4 * pp + 0], ox1 = OFFS_TAB.v[4 * pp + 1];
    int oy2 = OFFS_TAB.v[4 * pp + 2], ox2 = OFFS_TAB.v[4 * pp + 3];
    int ya = min(max(y + oy1, 0), IMH - 1), xa = min(max(x + ox1, 0), IMW - 1);
    int yb = min(max(y + oy2, 0), IMH - 1), xb = min(max(x + ox2, 0), IMW - 1);
    float v2 = sm[ya * IMW + xa] - sm[yb * IMW + xb];
    d[t2] = valid ? v2 : 0.f;
  }
  float ss = d[0] * d[0] + d[1] * d[1] + d[2] * d[2] + d[3] * d[3];
  #pragma unroll
  for (int off = 32; off; off >>= 1) ss += __shfl_down(ss, off);
  ss = __shfl(ss, 0);
  float scale = 1.f / (sqrtf(ss) + 1e-8f);
  float* dd = desc + (size_t)(b * KPT + k) * DESC;
  #pragma unroll
  for (int t2 = 0; t2 < 4; ++t2) dd[(lane << 2) + t2] = d[t2] * scale;
  if (lane == 0) {
    a2_out[b * KPT + k] = ss * scale * scale;
    float* kp = out + b * (2 * KPT) + k * 2;
    kp[0] = valid ? (float)y : -1.f;
    kp[1] = valid ? (float)x : -1.f;
  }
}

// ---------------------------------------------------------------- similarity: LDS-tiled GEMM, 512 blocks
// 32x16 tile/block, 128 threads, 2x2 regs/thread. Grid 32x16 = 512 blocks ->
// 2 blocks/CU co-resident. CK=128: 2 chunks, half the barriers. Accumulation
// strictly k-ascending. Kt is GONE: the fused sinkhorn reads K rows for the
// column reduction (coalesced), so the transposed copy is dead weight.
#define CK 128
#define APITCH 34
#define BPITCH 18
__global__ __launch_bounds__(128) void similarity_tiled_kernel(
    const float* __restrict__ desc, const float* __restrict__ a2,
    float* __restrict__ K) {
  __shared__ float As[CK * APITCH];   // [k][row], 32 rows
  __shared__ float Bs[CK * BPITCH];   // [k][col], 16 cols
  __shared__ float T[32 * 17];        // output tile for coalesced writes
  const int tid = threadIdx.x;
  const int tx = tid & 7;         // col-pair index (16 cols)
  const int ty = tid >> 3;        // row-pair index (32 rows)
  const int row0 = blockIdx.y * 32;
  const int col0 = blockIdx.x * 16;
  float acc[2][2] = {};
  for (int kc = 0; kc < DESC; kc += CK) {
    for (int i = tid; i < 32 * CK; i += 128) {
      int c = i & (CK - 1), r = i >> 7;   // consecutive lanes -> consecutive c: coalesced
      As[c * APITCH + r] = desc[(size_t)(row0 + r) * DESC + kc + c];
    }
    for (int i = tid; i < 16 * CK; i += 128) {
      int c = i & (CK - 1), r = i >> 7;
      Bs[c * BPITCH + r] = desc[(size_t)(KPT + col0 + r) * DESC + kc + c];
    }
    __syncthreads();
    #pragma unroll 16
    for (int kk = 0; kk < CK; ++kk) {
      const float2 av = *(const float2*)&As[kk * APITCH + ty * 2];
      const float2 bv = *(const float2*)&Bs[kk * BPITCH + tx * 2];
      acc[0][0] += av.x * bv.x; acc[0][1] += av.x * bv.y;
      acc[1][0] += av.y * bv.x; acc[1][1] += av.y * bv.y;
    }
    __syncthreads();
  }
  float a2k[2], b2l[2];
  #pragma unroll
  for (int i = 0; i < 2; ++i) {
    a2k[i] = a2[row0 + ty * 2 + i];
    b2l[i] = a2[KPT + col0 + tx * 2 + i];
  }
  #pragma unroll
  for (int i = 0; i < 2; ++i)
    #pragma unroll
    for (int j = 0; j < 2; ++j) {
      float sq = fmaxf(a2k[i] + b2l[j] - 2.f * acc[i][j], 0.f);
      T[(ty * 2 + i) * 17 + tx * 2 + j] = expf(-sqrtf(sq + 1e-12f));
    }
  __syncthreads();
  for (int i = tid; i < 512; i += 128) {
    int r = i >> 4, c = i & 15;
    K[(size_t)(row0 + r) * 513 + col0 + c] = T[r * 17 + c];
  }
}

// ---------------------------------------------------------------- sinkhorn, linear domain, FUSED iteration
// One dispatch per full iteration: a = mu / (K b); colsum = K^T a.
// R4's LDS-staged tile (proven -0.6 us/dispatch) at SB=1024 / SROWS=16 /
// 33 blocks: ONE row dot per wave (16 waves) — this fixes R2's mistake
// (R2 kept SB=512 so each wave did 2 SERIAL dots; the serial critical path
// was the +1.5 us/dispatch, not the row count). Halves block count and
// cs atomics (33k -> 17k). Stage stays ~8 loads/thread. Colsum regroups
// 8+8 -> 16 summands per atomic (ulp-level drift only).
#define SB 1024
#define SROWS 16
__global__ __launch_bounds__(SB) void sink_iter_kernel(
    const float* __restrict__ Kmat, const float* __restrict__ cs_prev,
    float* __restrict__ cs_next, float* __restrict__ cs_zero,
    float* __restrict__ a_out) {
  __shared__ float tile[SROWS * 513];   // 32.8 KB
  __shared__ float b_lds[513];
  __shared__ float a_lds[SROWS];
  const int tid = threadIdx.x;
  const int k0 = blockIdx.x * SROWS;
  const int nrows = min(SROWS, 513 - k0);      // last block (k0=512) has 1 row
  // K-tile stage: contiguous rows k0..k0+nrows-1, fully coalesced, issued first
  for (int i = tid; i < nrows * 513; i += SB)
    tile[i] = Kmat[(size_t)k0 * 513 + i];
  for (int l = tid; l < 513; l += SB) {
    float nu = (l == KPT) ? 0.5f : (1.0f / 1024.0f);
    b_lds[l] = nu / cs_prev[l];
  }
  if (blockIdx.x == 0) {
    for (int l = tid; l < 513; l += SB) cs_zero[l] = 0.f;
  }
  __syncthreads();
  // a-update: wave w owns row k0+w; same lane mapping + butterfly as R1/R4
  const int w = tid >> 6, lane = tid & 63;
  const int k = k0 + w;
  if (w < nrows) {
    const float* row = tile + w * 513;
    float s = 0.f;
    for (int i = lane; i < 513; i += 64) s += row[i] * b_lds[i];
    #pragma unroll
    for (int off = 32; off; off >>= 1) s += __shfl_xor(s, off);
    if (lane == 0) {
      float mu = (k == KPT) ? 0.5f : (1.0f / 1024.0f);
      float av = mu / s;
      a_lds[w] = av;
      a_out[k] = av;
    }
  }
  __syncthreads();
  // column partial from the LDS tile, w2 ascending
  for (int l = tid; l < 513; l += SB) {
    float p = 0.f;
    for (int w2 = 0; w2 < nrows; ++w2)
      p += a_lds[w2] * tile[w2 * 513 + l];
    atomicAdd(&cs_next[l], p);
  }
}

__global__ void probs_kernel(const float* __restrict__ K, const float* __restrict__ a,
                             const float* __restrict__ cs, float* __restrict__ out) {
  int t = blockIdx.x * blockDim.x + threadIdx.x;
  if (t >= 513 * 513) return;
  int k = t / 513;
  int l = t - k * 513;
  float nu = (l == KPT) ? 0.5f : (1.0f / 1024.0f);
  float b = nu / cs[l];
  out[t] = K[t] * (a[k] * 1024.f) * b;
}

// ---------------------------------------------------------------- launch
extern "C" void kernel_launch(void* const* d_in, const int* in_sizes, int n_in,
                              void* d_out, int out_size, void* d_ws, size_t ws_size,
                              hipStream_t stream) {
  const float* img1 = (const float*)d_in[0];
  const float* img2 = (const float*)d_in[1];
  float* out = (float*)d_out;

  char* p = (char*)d_ws;
  auto alloc = [&](size_t bytes) { char* r = p; p += (bytes + 255) & ~(size_t)255; return r; };
  int*   counts   = (int*)alloc(2 * 4);
  float* sel_val  = (float*)alloc(2 * KPT * 4);
  int*   sel_idx  = (int*)alloc(2 * KPT * 4);
  float* a_vec    = (float*)alloc(513 * 4);
  float* cs0      = (float*)alloc(513 * 4);
  float* cs1      = (float*)alloc(513 * 4);
  float* cs2      = (float*)alloc(513 * 4);
  float* a2       = (float*)alloc(2 * KPT * 4);
  int*   done     = (int*)alloc(128 * 4);
  float* smooth   = (float*)alloc((size_t)2 * HW * 4);
  float* cand_val = (float*)alloc((size_t)2 * CAP * 4);
  int*   cand_idx = (int*)alloc((size_t)2 * CAP * 4);
  int*   rank_arr = (int*)alloc((size_t)2 * CAP * 4);
  float* desc     = (float*)alloc((size_t)2 * KPT * DESC * 4);
  float* K        = (float*)alloc((size_t)513 * 513 * 4);

  init_misc_kernel<<<64, 256, 0, stream>>>(counts, sel_val, sel_idx, cs0, cs1, cs2,
                                           rank_arr, done, K);
  det_nms_kernel<<<dim3(IMW / FTW, IMH / FTH, 2), 256, 0, stream>>>(img1, img2, smooth,
                                                                    cand_val, cand_idx, counts);
  rank_partial_kernel<<<dim3(CAP / 256, CAP / 256, 2), 256, 0, stream>>>(
      cand_val, cand_idx, counts, rank_arr, done, sel_val, sel_idx);
  kp_desc_kernel<<<1024, 64, 0, stream>>>(sel_val, sel_idx, smooth, desc, a2, out);
  similarity_tiled_kernel<<<dim3(32, 16), 128, 0, stream>>>(desc, a2, K);
  float* bufs[3] = {cs0, cs1, cs2};
  for (int t = 0; t < 20; ++t) {
    sink_iter_kernel<<<(513 + SROWS - 1) / SROWS, SB, 0, stream>>>(
        K, bufs[(t + 2) % 3], bufs[t % 3], bufs[(t + 1) % 3], a_vec);
  }
  // final colsum lives in bufs[19 % 3] = cs1
  probs_kernel<<<(513 * 513 + 255) / 256, 256, 0, stream>>>(K, a_vec, bufs[19 % 3], out + 2048);
}

// Round 6
// 230.804 us; speedup vs baseline: 1.0547x; 1.0547x over previous
//
#include <hip/hip_runtime.h>
#include <math.h>

#define IMH 480
#define IMW 640
#define HW (IMH*IMW)
#define KPT 512
#define DESC 256
#define CAP 12288
#define NMSR 3

// ---------------------------------------------------------------- BAD offsets at COMPILE TIME
// np.random.RandomState(42).uniform(-8,8,(256,4)) -> np.round (half-to-even) -> int.
struct OffsTable { int v[1024]; };

constexpr unsigned mt_temper(unsigned y) {
  y ^= (y >> 11);
  y ^= (y << 7)  & 0x9d2c5680u;
  y ^= (y << 15) & 0xefc60000u;
  y ^= (y >> 18);
  return y;
}

constexpr OffsTable make_offs() {
  OffsTable T{};
  unsigned mt[624]{};
  unsigned s = 42u;
  for (int i = 0; i < 624; ++i) { mt[i] = s; s = 1812433253u * (s ^ (s >> 30)) + (unsigned)i + 1u; }
  int mti = 624;
  unsigned draws[2048]{};
  for (int i = 0; i < 2048; ++i) {
    if (mti >= 624) {
      for (int k = 0; k < 624; ++k) {
        unsigned y = (mt[k] & 0x80000000u) | (mt[(k + 1) % 624] & 0x7fffffffu);
        unsigned v = mt[(k + 397) % 624] ^ (y >> 1);
        if (y & 1u) v ^= 0x9908b0dfu;
        mt[k] = v;
      }
      mti = 0;
    }
    draws[i] = mt_temper(mt[mti++]);
  }
  for (int i = 0; i < 1024; ++i) {
    unsigned a = draws[2 * i] >> 5, b = draws[2 * i + 1] >> 6;
    double r = ((double)a * 67108864.0 + (double)b) / 9007199254740992.0;
    double val = -8.0 + 16.0 * r;
    double f = (double)(long long)val;
    if (val < f) f -= 1.0;                 // floor
    double diff = val - f;
    double rounded;
    if (diff > 0.5) rounded = f + 1.0;
    else if (diff < 0.5) rounded = f;
    else { long long fi = (long long)f; rounded = (fi % 2 == 0) ? f : f + 1.0; }  // half->even
    T.v[i] = (int)rounded;
  }
  return T;
}

__constant__ OffsTable OFFS_TAB = make_offs();

// ---------------------------------------------------------------- init
__global__ void init_misc_kernel(int* __restrict__ counts, float* __restrict__ sel_val,
                                 int* __restrict__ sel_idx,
                                 float* __restrict__ cs0, float* __restrict__ cs1,
                                 float* __restrict__ cs2,
                                 float* __restrict__ K) {
  int t = blockIdx.x * blockDim.x + threadIdx.x;
  if (t < 2) counts[t] = 0;
  if (t < 2 * KPT) { sel_val[t] = 0.f; sel_idx[t] = -1; }
  if (t < 513) {
    // triple-buffer colsum rotation: iteration t reads cs[(t+2)%3], atomically
    // accumulates cs[t%3], zeros cs[(t+1)%3]. Seed the first read buffer (cs2)
    // with nu so b0 = nu/cs2 = 1 (v=0 initial), zero the first write buffer.
    cs0[t] = 0.f;
    cs1[t] = 0.f;
    cs2[t] = (t == KPT) ? 0.5f : (1.0f / 1024.0f);
    // dustbin row/col of the linear-domain kernel matrix: exp(UNUSED/EPS)=exp(1)
    float e = expf(1.0f);
    K[(size_t)KPT * 513 + t] = e;
    K[(size_t)t * 513 + KPT] = e;
  }
}

// ---------------------------------------------------------------- fused detector + NMS
#define FTW 64
#define FTH 8
__global__ void det_nms_kernel(const float* __restrict__ img0, const float* __restrict__ img1,
                               float* __restrict__ smooth,
                               float* __restrict__ cand_val, int* __restrict__ cand_idx,
                               int* __restrict__ counts) {
  const int b = blockIdx.z;
  const int x0 = blockIdx.x * FTW;
  const int y0 = blockIdx.y * FTH;
  const float* __restrict__ img = b ? img1 : img0;
  __shared__ float im[(FTH + 10) * (FTW + 10)];   // 18 x 74 image stage (0 OOB)
  __shared__ float scs[(FTH + 6) * (FTW + 6)];    // 14 x 70 scores (-inf OOB)
  __shared__ float hm[(FTH + 6) * FTW];           // 14 x 64 horizontal 7-max
  __shared__ float lval[128];
  __shared__ int lidx[128];
  __shared__ int lcnt, gbase;
  const int tid = threadIdx.x;
  if (tid == 0) lcnt = 0;
  for (int i = tid; i < 18 * 74; i += 256) {
    int ly = i / 74, lx = i - ly * 74;
    int gy = y0 + ly - 5, gx = x0 + lx - 5;
    im[i] = (gy >= 0 && gy < IMH && gx >= 0 && gx < IMW) ? img[gy * IMW + gx] : 0.f;
  }
  __syncthreads();
  for (int i = tid; i < 14 * 70; i += 256) {
    int ly = i / 70, lx = i - ly * 70;
    int gy = y0 + ly - 3, gx = x0 + lx - 3;
    float sc;
    if (gy < 0 || gy >= IMH || gx < 0 || gx >= IMW) {
      sc = -INFINITY;                 // reference NMS pads with -inf
    } else {
      float a[5][5];
      #pragma unroll
      for (int ii = 0; ii < 5; ++ii)
        #pragma unroll
        for (int jj = 0; jj < 5; ++jj)
          a[ii][jj] = im[(ly + ii) * 74 + lx + jj];
      float sm = 0.f;
      #pragma unroll
      for (int ii = 0; ii < 5; ++ii)
        #pragma unroll
        for (int jj = 0; jj < 5; ++jj) sm += a[ii][jj];
      if (ly >= 3 && ly < 3 + FTH && lx >= 3 && lx < 3 + FTW)
        smooth[b * HW + gy * IMW + gx] = sm * (1.f / 25.f);
      float sxx = 0.f, syy = 0.f, sxy = 0.f;
      #pragma unroll
      for (int cy = -1; cy <= 1; ++cy) {
        #pragma unroll
        for (int cx = -1; cx <= 1; ++cx) {
          int yy = gy + cy, xx = gx + cx;
          if (yy < 0 || yy >= IMH || xx < 0 || xx >= IMW) continue;  // zero-pad box conv
          int iu = cy + 2, iv = cx + 2;
          float ix = (a[iu - 1][iv + 1] - a[iu - 1][iv - 1])
                   + 2.f * (a[iu][iv + 1] - a[iu][iv - 1])
                   + (a[iu + 1][iv + 1] - a[iu + 1][iv - 1]);
          float iy = (a[iu + 1][iv - 1] + 2.f * a[iu + 1][iv] + a[iu + 1][iv + 1])
                   - (a[iu - 1][iv - 1] + 2.f * a[iu - 1][iv] + a[iu - 1][iv + 1]);
          sxx += ix * ix; syy += iy * iy; sxy += ix * iy;
        }
      }
      sxx *= (1.f / 9.f); syy *= (1.f / 9.f); sxy *= (1.f / 9.f);
      float half_tr = 0.5f * (sxx + syy);
      float hd = 0.5f * (sxx - syy);
      sc = half_tr - sqrtf(hd * hd + sxy * sxy + 1e-12f);
    }
    scs[i] = sc;
  }
  __syncthreads();
  for (int i = tid; i < 14 * 64; i += 256) {
    int ly = i / 64, lx = i - ly * 64;
    const float* r = scs + ly * 70 + lx;
    float m = r[0];
    #pragma unroll
    for (int d = 1; d < 7; ++d) m = fmaxf(m, r[d]);
    hm[i] = m;
  }
  __syncthreads();
  for (int i = tid; i < FTH * FTW; i += 256) {
    int ly = i >> 6, lx = i & 63;
    float s = scs[(ly + 3) * 70 + lx + 3];
    if (s > 0.f) {
      float m = hm[ly * 64 + lx];
      #pragma unroll
      for (int d = 1; d < 7; ++d) m = fmaxf(m, hm[(ly + d) * 64 + lx]);
      if (s >= m - 1e-7f) {
        int slot = atomicAdd(&lcnt, 1);
        if (slot < 128) { lval[slot] = s; lidx[slot] = (y0 + ly) * IMW + (x0 + lx); }
      }
    }
  }
  __syncthreads();
  if (tid == 0) gbase = atomicAdd(&counts[b], min(lcnt, 128));
  __syncthreads();
  int nc = min(lcnt, 128);
  for (int i = tid; i < nc; i += 256) {
    int slot = gbase + i;
    if (slot < CAP) {
      cand_val[b * CAP + slot] = lval[i];
      cand_idx[b * CAP + slot] = lidx[i];
    }
  }
}

// ---------------------------------------------------------------- top-512 via sort + binary search
// Replaces the O(n^2) all-pairs rank count (measured ~20-33 us via R5's
// counter calibration) with per-chunk bitonic sort + per-candidate binary
// search: 8 LDS probes per chunk instead of 256 compares. Ranks are counts
// of strictly-greater keys -> order-independent -> bit-identical to the
// all-pairs version. Keys globally unique (score bits || ~idx); chunk pad
// keys are 0 (< every real key, contribute 0 -- same as before).

// per-256-chunk ascending bitonic sort of packed keys
__global__ void sort_chunks_kernel(const float* __restrict__ cand_val,
                                   const int* __restrict__ cand_idx,
                                   const int* __restrict__ counts,
                                   unsigned long long* __restrict__ skeys) {
  const int b = blockIdx.y;
  int n = counts[b]; if (n > CAP) n = CAP;
  const int J = blockIdx.x;
  if (J * 256 >= n) return;
  __shared__ unsigned long long s[256];
  const int tid = threadIdx.x;
  const int j = J * 256 + tid;
  s[tid] = (j < n)
      ? (((unsigned long long)__float_as_uint(cand_val[b * CAP + j]) << 32)
         | (0xFFFFFFFFu - (unsigned)cand_idx[b * CAP + j]))
      : 0ull;
  __syncthreads();
  for (unsigned k = 2; k <= 256; k <<= 1) {
    for (unsigned jj = k >> 1; jj > 0; jj >>= 1) {
      const unsigned ixj = (unsigned)tid ^ jj;
      if (ixj > (unsigned)tid) {
        const bool up = ((tid & k) == 0);
        unsigned long long A = s[tid], B = s[ixj];
        if (up ? (A > B) : (A < B)) { s[tid] = B; s[ixj] = A; }
      }
      __syncthreads();
    }
  }
  skeys[(size_t)b * CAP + J * 256 + tid] = s[tid];
}

// rank by summed upper_bound over sorted chunks; scatter fused in-tail
// (rank completes in-register per thread -- no rank_arr, no atomics, no
// fence; R5's cross-block-completion failure mode doesn't exist here).
#define RSB 1024
__global__ __launch_bounds__(RSB) void rank_scatter_kernel(
    const float* __restrict__ cand_val, const int* __restrict__ cand_idx,
    const int* __restrict__ counts, const unsigned long long* __restrict__ skeys,
    float* __restrict__ sel_val, int* __restrict__ sel_idx) {
  const int b = blockIdx.y;
  int n = counts[b]; if (n > CAP) n = CAP;
  const int i0 = blockIdx.x * RSB;
  if (i0 >= n) return;
  __shared__ unsigned long long s[256];
  const int tid = threadIdx.x;
  const int i = i0 + tid;
  unsigned long long ki = 0xFFFFFFFFFFFFFFFFull;   // inactive: search is cheap no-op
  float vi = 0.f; int di = -1;
  if (i < n) {
    vi = cand_val[b * CAP + i];
    di = cand_idx[b * CAP + i];
    ki = ((unsigned long long)__float_as_uint(vi) << 32) | (0xFFFFFFFFu - (unsigned)di);
  }
  int r = 0;
  const int NJ = (n + 255) >> 8;
  for (int J = 0; J < NJ; ++J) {
    if (tid < 256) s[tid] = skeys[(size_t)b * CAP + J * 256 + tid];
    __syncthreads();
    // count of keys strictly greater than ki = 256 - upper_bound(ki)
    int lo = 0, hi = 256;
    while (lo < hi) {
      int mid = (lo + hi) >> 1;
      if (s[mid] <= ki) lo = mid + 1; else hi = mid;
    }
    r += 256 - lo;
    __syncthreads();
  }
  if (i < n && r < KPT) {
    sel_val[b * KPT + r] = vi;
    sel_idx[b * KPT + r] = di;
  }
}

// ---------------------------------------------------------------- kp out + BAD desc + L2 norm
// 1024 blocks x 1 wave: one wave per keypoint. The random gather into smooth
// is latency-bound; maximal wave count is the right shape (R3's 4-wave fused
// variant concentrated 1024 gathers into 384 imbalanced waves -> +9 us).
__global__ void kp_desc_kernel(const float* __restrict__ sel_val, const int* __restrict__ sel_idx,
                               const float* __restrict__ smooth,
                               float* __restrict__ desc, float* __restrict__ a2_out,
                               float* __restrict__ out) {
  int blk = blockIdx.x;
  int b = blk >> 9;
  int k = blk & 511;
  int lane = threadIdx.x;
  float val = sel_val[b * KPT + k];
  int idx = sel_idx[b * KPT + k];
  bool valid = (val > 0.f) && (idx >= 0);
  int y = 0, x = 0;
  if (valid) { y = idx / IMW; x = idx - y * IMW; }
  const float* sm = smooth + b * HW;
  float d[4];
  #pragma unroll
  for (int t2 = 0; t2 < 4; ++t2) {
    int pp = (lane << 2) + t2;
    int oy1 = OFFS_TAB.v[4 * pp + 0], ox1 = OFFS_TAB.v[4 * pp + 1];
    int oy2 = OFFS_TAB.v[4 * pp + 2], ox2 = OFFS_TAB.v[4 * pp + 3];
    int ya = min(max(y + oy1, 0), IMH - 1), xa = min(max(x + ox1, 0), IMW - 1);
    int yb = min(max(y + oy2, 0), IMH - 1), xb = min(max(x + ox2, 0), IMW - 1);
    float v2 = sm[ya * IMW + xa] - sm[yb * IMW + xb];
    d[t2] = valid ? v2 : 0.f;
  }
  float ss = d[0] * d[0] + d[1] * d[1] + d[2] * d[2] + d[3] * d[3];
  #pragma unroll
  for (int off = 32; off; off >>= 1) ss += __shfl_down(ss, off);
  ss = __shfl(ss, 0);
  float scale = 1.f / (sqrtf(ss) + 1e-8f);
  float* dd = desc + (size_t)(b * KPT + k) * DESC;
  #pragma unroll
  for (int t2 = 0; t2 < 4; ++t2) dd[(lane << 2) + t2] = d[t2] * scale;
  if (lane == 0) {
    a2_out[b * KPT + k] = ss * scale * scale;
    float* kp = out + b * (2 * KPT) + k * 2;
    kp[0] = valid ? (float)y : -1.f;
    kp[1] = valid ? (float)x : -1.f;
  }
}

// ---------------------------------------------------------------- similarity: LDS-tiled GEMM, 512 blocks
// 32x16 tile/block, 128 threads, 2x2 regs/thread. Grid 32x16 = 512 blocks ->
// 2 blocks/CU co-resident. CK=128: 2 chunks, half the barriers. Accumulation
// strictly k-ascending. Kt is GONE: the fused sinkhorn reads K rows for the
// column reduction (coalesced), so the transposed copy is dead weight.
#define CK 128
#define APITCH 34
#define BPITCH 18
__global__ __launch_bounds__(128) void similarity_tiled_kernel(
    const float* __restrict__ desc, const float* __restrict__ a2,
    float* __restrict__ K) {
  __shared__ float As[CK * APITCH];   // [k][row], 32 rows
  __shared__ float Bs[CK * BPITCH];   // [k][col], 16 cols
  __shared__ float T[32 * 17];        // output tile for coalesced writes
  const int tid = threadIdx.x;
  const int tx = tid & 7;         // col-pair index (16 cols)
  const int ty = tid >> 3;        // row-pair index (32 rows)
  const int row0 = blockIdx.y * 32;
  const int col0 = blockIdx.x * 16;
  float acc[2][2] = {};
  for (int kc = 0; kc < DESC; kc += CK) {
    for (int i = tid; i < 32 * CK; i += 128) {
      int c = i & (CK - 1), r = i >> 7;   // consecutive lanes -> consecutive c: coalesced
      As[c * APITCH + r] = desc[(size_t)(row0 + r) * DESC + kc + c];
    }
    for (int i = tid; i < 16 * CK; i += 128) {
      int c = i & (CK - 1), r = i >> 7;
      Bs[c * BPITCH + r] = desc[(size_t)(KPT + col0 + r) * DESC + kc + c];
    }
    __syncthreads();
    #pragma unroll 16
    for (int kk = 0; kk < CK; ++kk) {
      const float2 av = *(const float2*)&As[kk * APITCH + ty * 2];
      const float2 bv = *(const float2*)&Bs[kk * BPITCH + tx * 2];
      acc[0][0] += av.x * bv.x; acc[0][1] += av.x * bv.y;
      acc[1][0] += av.y * bv.x; acc[1][1] += av.y * bv.y;
    }
    __syncthreads();
  }
  float a2k[2], b2l[2];
  #pragma unroll
  for (int i = 0; i < 2; ++i) {
    a2k[i] = a2[row0 + ty * 2 + i];
    b2l[i] = a2[KPT + col0 + tx * 2 + i];
  }
  #pragma unroll
  for (int i = 0; i < 2; ++i)
    #pragma unroll
    for (int j = 0; j < 2; ++j) {
      float sq = fmaxf(a2k[i] + b2l[j] - 2.f * acc[i][j], 0.f);
      T[(ty * 2 + i) * 17 + tx * 2 + j] = expf(-sqrtf(sq + 1e-12f));
    }
  __syncthreads();
  for (int i = tid; i < 512; i += 128) {
    int r = i >> 4, c = i & 15;
    K[(size_t)(row0 + r) * 513 + col0 + c] = T[r * 17 + c];
  }
}

// ---------------------------------------------------------------- sinkhorn, linear domain, FUSED iteration
// One dispatch per full iteration: a = mu / (K b); colsum = K^T a.
// R4-proven configuration: SROWS=8 / SB=512 / 65 blocks, K-tile staged into
// LDS once (coalesced, issued at kernel entry, overlapping the cs_prev load
// + b compute); both phases read the tile from LDS. One row dot per wave.
// (R2/R5 variants with taller blocks or serial dots regressed: these
// dispatches are latency-bound, per-block critical path is the metric.)
// Triple-buffer rotation: read cs[(t+2)%3], accumulate cs[t%3], zero
// cs[(t+1)%3] — the zeroed buffer is never touched by this dispatch's
// readers/writers; dispatch boundary orders it for iteration t+1.
#define SB 512
#define SROWS 8
__global__ __launch_bounds__(SB) void sink_iter_kernel(
    const float* __restrict__ Kmat, const float* __restrict__ cs_prev,
    float* __restrict__ cs_next, float* __restrict__ cs_zero,
    float* __restrict__ a_out) {
  __shared__ float tile[SROWS * 513];
  __shared__ float b_lds[513];
  __shared__ float a_lds[SROWS];
  const int tid = threadIdx.x;
  const int k0 = blockIdx.x * SROWS;
  const int nrows = min(SROWS, 513 - k0);      // last block (k0=512) has 1 row
  // K-tile stage: contiguous rows k0..k0+nrows-1, fully coalesced, issued first
  for (int i = tid; i < nrows * 513; i += SB)
    tile[i] = Kmat[(size_t)k0 * 513 + i];
  for (int l = tid; l < 513; l += SB) {
    float nu = (l == KPT) ? 0.5f : (1.0f / 1024.0f);
    b_lds[l] = nu / cs_prev[l];
  }
  if (blockIdx.x == 0) {
    for (int l = tid; l < 513; l += SB) cs_zero[l] = 0.f;
  }
  __syncthreads();
  // a-update: wave w owns row k0+w; same lane mapping + butterfly as R1/R4
  const int w = tid >> 6, lane = tid & 63;
  const int k = k0 + w;
  if (w < nrows) {
    const float* row = tile + w * 513;
    float s = 0.f;
    for (int i = lane; i < 513; i += 64) s += row[i] * b_lds[i];
    #pragma unroll
    for (int off = 32; off; off >>= 1) s += __shfl_xor(s, off);
    if (lane == 0) {
      float mu = (k == KPT) ? 0.5f : (1.0f / 1024.0f);
      float av = mu / s;
      a_lds[w] = av;
      a_out[k] = av;
    }
  }
  __syncthreads();
  // column partial from the LDS tile, w2 ascending (same order as R1/R4)
  for (int l = tid; l < 513; l += SB) {
    float p = 0.f;
    for (int w2 = 0; w2 < nrows; ++w2)
      p += a_lds[w2] * tile[w2 * 513 + l];
    atomicAdd(&cs_next[l], p);
  }
}

__global__ void probs_kernel(const float* __restrict__ K, const float* __restrict__ a,
                             const float* __restrict__ cs, float* __restrict__ out) {
  int t = blockIdx.x * blockDim.x + threadIdx.x;
  if (t >= 513 * 513) return;
  int k = t / 513;
  int l = t - k * 513;
  float nu = (l == KPT) ? 0.5f : (1.0f / 1024.0f);
  float b = nu / cs[l];
  out[t] = K[t] * (a[k] * 1024.f) * b;
}

// ---------------------------------------------------------------- launch
extern "C" void kernel_launch(void* const* d_in, const int* in_sizes, int n_in,
                              void* d_out, int out_size, void* d_ws, size_t ws_size,
                              hipStream_t stream) {
  const float* img1 = (const float*)d_in[0];
  const float* img2 = (const float*)d_in[1];
  float* out = (float*)d_out;

  char* p = (char*)d_ws;
  auto alloc = [&](size_t bytes) { char* r = p; p += (bytes + 255) & ~(size_t)255; return r; };
  int*   counts   = (int*)alloc(2 * 4);
  float* sel_val  = (float*)alloc(2 * KPT * 4);
  int*   sel_idx  = (int*)alloc(2 * KPT * 4);
  float* a_vec    = (float*)alloc(513 * 4);
  float* cs0      = (float*)alloc(513 * 4);
  float* cs1      = (float*)alloc(513 * 4);
  float* cs2      = (float*)alloc(513 * 4);
  float* a2       = (float*)alloc(2 * KPT * 4);
  float* smooth   = (float*)alloc((size_t)2 * HW * 4);
  float* cand_val = (float*)alloc((size_t)2 * CAP * 4);
  int*   cand_idx = (int*)alloc((size_t)2 * CAP * 4);
  unsigned long long* skeys = (unsigned long long*)alloc((size_t)2 * CAP * 8);
  float* desc     = (float*)alloc((size_t)2 * KPT * DESC * 4);
  float* K        = (float*)alloc((size_t)513 * 513 * 4);

  init_misc_kernel<<<64, 256, 0, stream>>>(counts, sel_val, sel_idx, cs0, cs1, cs2, K);
  det_nms_kernel<<<dim3(IMW / FTW, IMH / FTH, 2), 256, 0, stream>>>(img1, img2, smooth,
                                                                    cand_val, cand_idx, counts);
  sort_chunks_kernel<<<dim3(CAP / 256, 2), 256, 0, stream>>>(cand_val, cand_idx, counts, skeys);
  rank_scatter_kernel<<<dim3(CAP / RSB, 2), RSB, 0, stream>>>(cand_val, cand_idx, counts, skeys,
                                                              sel_val, sel_idx);
  kp_desc_kernel<<<1024, 64, 0, stream>>>(sel_val, sel_idx, smooth, desc, a2, out);
  similarity_tiled_kernel<<<dim3(32, 16), 128, 0, stream>>>(desc, a2, K);
  float* bufs[3] = {cs0, cs1, cs2};
  for (int t = 0; t < 20; ++t) {
    sink_iter_kernel<<<65, SB, 0, stream>>>(
        K, bufs[(t + 2) % 3], bufs[t % 3], bufs[(t + 1) % 3], a_vec);
  }
  // final colsum lives in bufs[19 % 3] = cs1
  probs_kernel<<<(513 * 513 + 255) / 256, 256, 0, stream>>>(K, a_vec, bufs[19 % 3], out + 2048);
}

// Round 7
// 204.066 us; speedup vs baseline: 1.1929x; 1.1310x over previous
//
#include <hip/hip_runtime.h>
#include <math.h>

#define IMH 480
#define IMW 640
#define HW (IMH*IMW)
#define KPT 512
#define DESC 256
#define CAP 12288
#define NMSR 3

// ---------------------------------------------------------------- BAD offsets at COMPILE TIME
// np.random.RandomState(42).uniform(-8,8,(256,4)) -> np.round (half-to-even) -> int.
struct OffsTable { int v[1024]; };

constexpr unsigned mt_temper(unsigned y) {
  y ^= (y >> 11);
  y ^= (y << 7)  & 0x9d2c5680u;
  y ^= (y << 15) & 0xefc60000u;
  y ^= (y >> 18);
  return y;
}

constexpr OffsTable make_offs() {
  OffsTable T{};
  unsigned mt[624]{};
  unsigned s = 42u;
  for (int i = 0; i < 624; ++i) { mt[i] = s; s = 1812433253u * (s ^ (s >> 30)) + (unsigned)i + 1u; }
  int mti = 624;
  unsigned draws[2048]{};
  for (int i = 0; i < 2048; ++i) {
    if (mti >= 624) {
      for (int k = 0; k < 624; ++k) {
        unsigned y = (mt[k] & 0x80000000u) | (mt[(k + 1) % 624] & 0x7fffffffu);
        unsigned v = mt[(k + 397) % 624] ^ (y >> 1);
        if (y & 1u) v ^= 0x9908b0dfu;
        mt[k] = v;
      }
      mti = 0;
    }
    draws[i] = mt_temper(mt[mti++]);
  }
  for (int i = 0; i < 1024; ++i) {
    unsigned a = draws[2 * i] >> 5, b = draws[2 * i + 1] >> 6;
    double r = ((double)a * 67108864.0 + (double)b) / 9007199254740992.0;
    double val = -8.0 + 16.0 * r;
    double f = (double)(long long)val;
    if (val < f) f -= 1.0;                 // floor
    double diff = val - f;
    double rounded;
    if (diff > 0.5) rounded = f + 1.0;
    else if (diff < 0.5) rounded = f;
    else { long long fi = (long long)f; rounded = (fi % 2 == 0) ? f : f + 1.0; }  // half->even
    T.v[i] = (int)rounded;
  }
  return T;
}

__constant__ OffsTable OFFS_TAB = make_offs();

// ---------------------------------------------------------------- init
__global__ void init_misc_kernel(int* __restrict__ counts, float* __restrict__ sel_val,
                                 int* __restrict__ sel_idx,
                                 float* __restrict__ cs0, float* __restrict__ cs1,
                                 float* __restrict__ cs2,
                                 int* __restrict__ rank_arr, float* __restrict__ K) {
  int t = blockIdx.x * blockDim.x + threadIdx.x;
  if (t < 2) counts[t] = 0;
  if (t < 2 * KPT) { sel_val[t] = 0.f; sel_idx[t] = -1; }
  if (t < 513) {
    // triple-buffer colsum rotation: iteration t reads cs[(t+2)%3], atomically
    // accumulates cs[t%3], zeros cs[(t+1)%3]. Seed the first read buffer (cs2)
    // with nu so b0 = nu/cs2 = 1 (v=0 initial), zero the first write buffer.
    cs0[t] = 0.f;
    cs1[t] = 0.f;
    cs2[t] = (t == KPT) ? 0.5f : (1.0f / 1024.0f);
    // dustbin row/col of the linear-domain kernel matrix: exp(UNUSED/EPS)=exp(1)
    float e = expf(1.0f);
    K[(size_t)KPT * 513 + t] = e;
    K[(size_t)t * 513 + KPT] = e;
  }
  for (int i = t; i < 2 * CAP; i += 16384) rank_arr[i] = 0;
}

// ---------------------------------------------------------------- fused detector + NMS
// FTH=16 (was 8): score stencil computes (FTH+6)x(FTW+6) to emit FTHxFTW;
// halo redundancy 1.91x -> 1.50x on the LDS-read-bound score loop, and
// block count halves. All bounds parametric; per-block maxima <= 85 (4x4
// packing bound for radius-3 NMS) stays under the 128-slot cap. Per-pixel
// math identical -> candidate key multiset identical -> downstream bit-same.
#define FTW 64
#define FTH 16
__global__ void det_nms_kernel(const float* __restrict__ img0, const float* __restrict__ img1,
                               float* __restrict__ smooth,
                               float* __restrict__ cand_val, int* __restrict__ cand_idx,
                               int* __restrict__ counts) {
  const int b = blockIdx.z;
  const int x0 = blockIdx.x * FTW;
  const int y0 = blockIdx.y * FTH;
  const float* __restrict__ img = b ? img1 : img0;
  __shared__ float im[(FTH + 10) * (FTW + 10)];   // 26 x 74 image stage (0 OOB)
  __shared__ float scs[(FTH + 6) * (FTW + 6)];    // 22 x 70 scores (-inf OOB)
  __shared__ float hm[(FTH + 6) * FTW];           // 22 x 64 horizontal 7-max
  __shared__ float lval[128];
  __shared__ int lidx[128];
  __shared__ int lcnt, gbase;
  const int tid = threadIdx.x;
  if (tid == 0) lcnt = 0;
  for (int i = tid; i < (FTH + 10) * 74; i += 256) {
    int ly = i / 74, lx = i - ly * 74;
    int gy = y0 + ly - 5, gx = x0 + lx - 5;
    im[i] = (gy >= 0 && gy < IMH && gx >= 0 && gx < IMW) ? img[gy * IMW + gx] : 0.f;
  }
  __syncthreads();
  for (int i = tid; i < (FTH + 6) * 70; i += 256) {
    int ly = i / 70, lx = i - ly * 70;
    int gy = y0 + ly - 3, gx = x0 + lx - 3;
    float sc;
    if (gy < 0 || gy >= IMH || gx < 0 || gx >= IMW) {
      sc = -INFINITY;                 // reference NMS pads with -inf
    } else {
      float a[5][5];
      #pragma unroll
      for (int ii = 0; ii < 5; ++ii)
        #pragma unroll
        for (int jj = 0; jj < 5; ++jj)
          a[ii][jj] = im[(ly + ii) * 74 + lx + jj];
      float sm = 0.f;
      #pragma unroll
      for (int ii = 0; ii < 5; ++ii)
        #pragma unroll
        for (int jj = 0; jj < 5; ++jj) sm += a[ii][jj];
      if (ly >= 3 && ly < 3 + FTH && lx >= 3 && lx < 3 + FTW)
        smooth[b * HW + gy * IMW + gx] = sm * (1.f / 25.f);
      float sxx = 0.f, syy = 0.f, sxy = 0.f;
      #pragma unroll
      for (int cy = -1; cy <= 1; ++cy) {
        #pragma unroll
        for (int cx = -1; cx <= 1; ++cx) {
          int yy = gy + cy, xx = gx + cx;
          if (yy < 0 || yy >= IMH || xx < 0 || xx >= IMW) continue;  // zero-pad box conv
          int iu = cy + 2, iv = cx + 2;
          float ix = (a[iu - 1][iv + 1] - a[iu - 1][iv - 1])
                   + 2.f * (a[iu][iv + 1] - a[iu][iv - 1])
                   + (a[iu + 1][iv + 1] - a[iu + 1][iv - 1]);
          float iy = (a[iu + 1][iv - 1] + 2.f * a[iu + 1][iv] + a[iu + 1][iv + 1])
                   - (a[iu - 1][iv - 1] + 2.f * a[iu - 1][iv] + a[iu - 1][iv + 1]);
          sxx += ix * ix; syy += iy * iy; sxy += ix * iy;
        }
      }
      sxx *= (1.f / 9.f); syy *= (1.f / 9.f); sxy *= (1.f / 9.f);
      float half_tr = 0.5f * (sxx + syy);
      float hd = 0.5f * (sxx - syy);
      sc = half_tr - sqrtf(hd * hd + sxy * sxy + 1e-12f);
    }
    scs[i] = sc;
  }
  __syncthreads();
  for (int i = tid; i < (FTH + 6) * 64; i += 256) {
    int ly = i / 64, lx = i - ly * 64;
    const float* r = scs + ly * 70 + lx;
    float m = r[0];
    #pragma unroll
    for (int d = 1; d < 7; ++d) m = fmaxf(m, r[d]);
    hm[i] = m;
  }
  __syncthreads();
  for (int i = tid; i < FTH * FTW; i += 256) {
    int ly = i >> 6, lx = i & 63;
    float s = scs[(ly + 3) * 70 + lx + 3];
    if (s > 0.f) {
      float m = hm[ly * 64 + lx];
      #pragma unroll
      for (int d = 1; d < 7; ++d) m = fmaxf(m, hm[(ly + d) * 64 + lx]);
      if (s >= m - 1e-7f) {
        int slot = atomicAdd(&lcnt, 1);
        if (slot < 128) { lval[slot] = s; lidx[slot] = (y0 + ly) * IMW + (x0 + lx); }
      }
    }
  }
  __syncthreads();
  if (tid == 0) gbase = atomicAdd(&counts[b], min(lcnt, 128));
  __syncthreads();
  int nc = min(lcnt, 128);
  for (int i = tid; i < nc; i += 256) {
    int slot = gbase + i;
    if (slot < CAP) {
      cand_val[b * CAP + slot] = lval[i];
      cand_idx[b * CAP + slot] = lidx[i];
    }
  }
}

// ---------------------------------------------------------------- top-512: 2D-tiled rank count
// (R6 lesson: the sort+binary-search alternative concentrated the rank into
// ~14 serial-loop blocks -> latency chain, +23 us. This all-pairs version is
// ~4-5 us of VALU spread over ~1250 blocks — block count IS the resource.)
__global__ void rank_partial_kernel(const float* __restrict__ cand_val,
                                    const int* __restrict__ cand_idx,
                                    const int* __restrict__ counts,
                                    int* __restrict__ rank_arr) {
  int b = blockIdx.z;
  int n = counts[b]; if (n > CAP) n = CAP;
  if ((int)(blockIdx.x * 256) >= n || (int)(blockIdx.y * 256) >= n) return;
  const float* cv = cand_val + b * CAP;
  const int* ci = cand_idx + b * CAP;
  int i = blockIdx.x * 256 + threadIdx.x;
  int j = blockIdx.y * 256 + threadIdx.x;
  __shared__ unsigned long long sk[256];
  sk[threadIdx.x] = (j < n)
      ? (((unsigned long long)__float_as_uint(cv[j]) << 32) | (0xFFFFFFFFu - (unsigned)ci[j]))
      : 0ull;
  __syncthreads();
  if (i >= n) return;
  unsigned long long ki = ((unsigned long long)__float_as_uint(cv[i]) << 32)
                        | (0xFFFFFFFFu - (unsigned)ci[i]);
  int r = 0;
  #pragma unroll 8
  for (int t = 0; t < 256; ++t) r += (sk[t] > ki) ? 1 : 0;
  atomicAdd(&rank_arr[b * CAP + i], r);
}

__global__ void scatter_topk_kernel(const float* __restrict__ cand_val,
                                    const int* __restrict__ cand_idx,
                                    const int* __restrict__ counts,
                                    const int* __restrict__ rank_arr,
                                    float* __restrict__ sel_val, int* __restrict__ sel_idx) {
  int b = blockIdx.y;
  int n = counts[b]; if (n > CAP) n = CAP;
  int i = blockIdx.x * 256 + threadIdx.x;
  if (i >= n) return;
  int r = rank_arr[b * CAP + i];
  if (r < KPT) {
    sel_val[b * KPT + r] = cand_val[b * CAP + i];
    sel_idx[b * KPT + r] = cand_idx[b * CAP + i];
  }
}

// ---------------------------------------------------------------- kp out + BAD desc + L2 norm
// 1024 blocks x 1 wave: one wave per keypoint. The random gather into smooth
// is latency-bound; maximal wave count is the right shape (R3's 4-wave fused
// variant concentrated 1024 gathers into 384 imbalanced waves -> +9 us).
__global__ void kp_desc_kernel(const float* __restrict__ sel_val, const int* __restrict__ sel_idx,
                               const float* __restrict__ smooth,
                               float* __restrict__ desc, float* __restrict__ a2_out,
                               float* __restrict__ out) {
  int blk = blockIdx.x;
  int b = blk >> 9;
  int k = blk & 511;
  int lane = threadIdx.x;
  float val = sel_val[b * KPT + k];
  int idx = sel_idx[b * KPT + k];
  bool valid = (val > 0.f) && (idx >= 0);
  int y = 0, x = 0;
  if (valid) { y = idx / IMW; x = idx - y * IMW; }
  const float* sm = smooth + b * HW;
  float d[4];
  #pragma unroll
  for (int t2 = 0; t2 < 4; ++t2) {
    int pp = (lane << 2) + t2;
    int oy1 = OFFS_TAB.v[4 * pp + 0], ox1 = OFFS_TAB.v[4 * pp + 1];
    int oy2 = OFFS_TAB.v[4 * pp + 2], ox2 = OFFS_TAB.v[4 * pp + 3];
    int ya = min(max(y + oy1, 0), IMH - 1), xa = min(max(x + ox1, 0), IMW - 1);
    int yb = min(max(y + oy2, 0), IMH - 1), xb = min(max(x + ox2, 0), IMW - 1);
    float v2 = sm[ya * IMW + xa] - sm[yb * IMW + xb];
    d[t2] = valid ? v2 : 0.f;
  }
  float ss = d[0] * d[0] + d[1] * d[1] + d[2] * d[2] + d[3] * d[3];
  #pragma unroll
  for (int off = 32; off; off >>= 1) ss += __shfl_down(ss, off);
  ss = __shfl(ss, 0);
  float scale = 1.f / (sqrtf(ss) + 1e-8f);
  float* dd = desc + (size_t)(b * KPT + k) * DESC;
  #pragma unroll
  for (int t2 = 0; t2 < 4; ++t2) dd[(lane << 2) + t2] = d[t2] * scale;
  if (lane == 0) {
    a2_out[b * KPT + k] = ss * scale * scale;
    float* kp = out + b * (2 * KPT) + k * 2;
    kp[0] = valid ? (float)y : -1.f;
    kp[1] = valid ? (float)x : -1.f;
  }
}

// ---------------------------------------------------------------- similarity: LDS-tiled GEMM, 512 blocks
// 32x16 tile/block, 128 threads, 2x2 regs/thread. Grid 32x16 = 512 blocks ->
// 2 blocks/CU co-resident. CK=128: 2 chunks, half the barriers. Accumulation
// strictly k-ascending. Kt is GONE: the fused sinkhorn reads K rows for the
// column reduction (coalesced), so the transposed copy is dead weight.
#define CK 128
#define APITCH 34
#define BPITCH 18
__global__ __launch_bounds__(128) void similarity_tiled_kernel(
    const float* __restrict__ desc, const float* __restrict__ a2,
    float* __restrict__ K) {
  __shared__ float As[CK * APITCH];   // [k][row], 32 rows
  __shared__ float Bs[CK * BPITCH];   // [k][col], 16 cols
  __shared__ float T[32 * 17];        // output tile for coalesced writes
  const int tid = threadIdx.x;
  const int tx = tid & 7;         // col-pair index (16 cols)
  const int ty = tid >> 3;        // row-pair index (32 rows)
  const int row0 = blockIdx.y * 32;
  const int col0 = blockIdx.x * 16;
  float acc[2][2] = {};
  for (int kc = 0; kc < DESC; kc += CK) {
    for (int i = tid; i < 32 * CK; i += 128) {
      int c = i & (CK - 1), r = i >> 7;   // consecutive lanes -> consecutive c: coalesced
      As[c * APITCH + r] = desc[(size_t)(row0 + r) * DESC + kc + c];
    }
    for (int i = tid; i < 16 * CK; i += 128) {
      int c = i & (CK - 1), r = i >> 7;
      Bs[c * BPITCH + r] = desc[(size_t)(KPT + col0 + r) * DESC + kc + c];
    }
    __syncthreads();
    #pragma unroll 16
    for (int kk = 0; kk < CK; ++kk) {
      const float2 av = *(const float2*)&As[kk * APITCH + ty * 2];
      const float2 bv = *(const float2*)&Bs[kk * BPITCH + tx * 2];
      acc[0][0] += av.x * bv.x; acc[0][1] += av.x * bv.y;
      acc[1][0] += av.y * bv.x; acc[1][1] += av.y * bv.y;
    }
    __syncthreads();
  }
  float a2k[2], b2l[2];
  #pragma unroll
  for (int i = 0; i < 2; ++i) {
    a2k[i] = a2[row0 + ty * 2 + i];
    b2l[i] = a2[KPT + col0 + tx * 2 + i];
  }
  #pragma unroll
  for (int i = 0; i < 2; ++i)
    #pragma unroll
    for (int j = 0; j < 2; ++j) {
      float sq = fmaxf(a2k[i] + b2l[j] - 2.f * acc[i][j], 0.f);
      T[(ty * 2 + i) * 17 + tx * 2 + j] = expf(-sqrtf(sq + 1e-12f));
    }
  __syncthreads();
  for (int i = tid; i < 512; i += 128) {
    int r = i >> 4, c = i & 15;
    K[(size_t)(row0 + r) * 513 + col0 + c] = T[r * 17 + c];
  }
}

// ---------------------------------------------------------------- sinkhorn, linear domain, FUSED iteration
// One dispatch per full iteration: a = mu / (K b); colsum = K^T a.
// R4-proven configuration: SROWS=8 / SB=512 / 65 blocks, K-tile staged into
// LDS once (coalesced, issued at kernel entry, overlapping the cs_prev load
// + b compute); both phases read the tile from LDS. One row dot per wave.
// (R2/R5 variants with taller blocks or serial dots regressed: these
// dispatches are latency-bound, per-block critical path is the metric.)
// Triple-buffer rotation: read cs[(t+2)%3], accumulate cs[t%3], zero
// cs[(t+1)%3] — the zeroed buffer is never touched by this dispatch's
// readers/writers; dispatch boundary orders it for iteration t+1.
#define SB 512
#define SROWS 8
__global__ __launch_bounds__(SB) void sink_iter_kernel(
    const float* __restrict__ Kmat, const float* __restrict__ cs_prev,
    float* __restrict__ cs_next, float* __restrict__ cs_zero,
    float* __restrict__ a_out) {
  __shared__ float tile[SROWS * 513];
  __shared__ float b_lds[513];
  __shared__ float a_lds[SROWS];
  const int tid = threadIdx.x;
  const int k0 = blockIdx.x * SROWS;
  const int nrows = min(SROWS, 513 - k0);      // last block (k0=512) has 1 row
  // K-tile stage: contiguous rows k0..k0+nrows-1, fully coalesced, issued first
  for (int i = tid; i < nrows * 513; i += SB)
    tile[i] = Kmat[(size_t)k0 * 513 + i];
  for (int l = tid; l < 513; l += SB) {
    float nu = (l == KPT) ? 0.5f : (1.0f / 1024.0f);
    b_lds[l] = nu / cs_prev[l];
  }
  if (blockIdx.x == 0) {
    for (int l = tid; l < 513; l += SB) cs_zero[l] = 0.f;
  }
  __syncthreads();
  // a-update: wave w owns row k0+w; same lane mapping + butterfly as R1/R4
  const int w = tid >> 6, lane = tid & 63;
  const int k = k0 + w;
  if (w < nrows) {
    const float* row = tile + w * 513;
    float s = 0.f;
    for (int i = lane; i < 513; i += 64) s += row[i] * b_lds[i];
    #pragma unroll
    for (int off = 32; off; off >>= 1) s += __shfl_xor(s, off);
    if (lane == 0) {
      float mu = (k == KPT) ? 0.5f : (1.0f / 1024.0f);
      float av = mu / s;
      a_lds[w] = av;
      a_out[k] = av;
    }
  }
  __syncthreads();
  // column partial from the LDS tile, w2 ascending (same order as R1/R4)
  for (int l = tid; l < 513; l += SB) {
    float p = 0.f;
    for (int w2 = 0; w2 < nrows; ++w2)
      p += a_lds[w2] * tile[w2 * 513 + l];
    atomicAdd(&cs_next[l], p);
  }
}

__global__ void probs_kernel(const float* __restrict__ K, const float* __restrict__ a,
                             const float* __restrict__ cs, float* __restrict__ out) {
  int t = blockIdx.x * blockDim.x + threadIdx.x;
  if (t >= 513 * 513) return;
  int k = t / 513;
  int l = t - k * 513;
  float nu = (l == KPT) ? 0.5f : (1.0f / 1024.0f);
  float b = nu / cs[l];
  out[t] = K[t] * (a[k] * 1024.f) * b;
}

// ---------------------------------------------------------------- launch
extern "C" void kernel_launch(void* const* d_in, const int* in_sizes, int n_in,
                              void* d_out, int out_size, void* d_ws, size_t ws_size,
                              hipStream_t stream) {
  const float* img1 = (const float*)d_in[0];
  const float* img2 = (const float*)d_in[1];
  float* out = (float*)d_out;

  char* p = (char*)d_ws;
  auto alloc = [&](size_t bytes) { char* r = p; p += (bytes + 255) & ~(size_t)255; return r; };
  int*   counts   = (int*)alloc(2 * 4);
  float* sel_val  = (float*)alloc(2 * KPT * 4);
  int*   sel_idx  = (int*)alloc(2 * KPT * 4);
  float* a_vec    = (float*)alloc(513 * 4);
  float* cs0      = (float*)alloc(513 * 4);
  float* cs1      = (float*)alloc(513 * 4);
  float* cs2      = (float*)alloc(513 * 4);
  float* a2       = (float*)alloc(2 * KPT * 4);
  float* smooth   = (float*)alloc((size_t)2 * HW * 4);
  float* cand_val = (float*)alloc((size_t)2 * CAP * 4);
  int*   cand_idx = (int*)alloc((size_t)2 * CAP * 4);
  int*   rank_arr = (int*)alloc((size_t)2 * CAP * 4);
  float* desc     = (float*)alloc((size_t)2 * KPT * DESC * 4);
  float* K        = (float*)alloc((size_t)513 * 513 * 4);

  init_misc_kernel<<<64, 256, 0, stream>>>(counts, sel_val, sel_idx, cs0, cs1, cs2, rank_arr, K);
  det_nms_kernel<<<dim3(IMW / FTW, IMH / FTH, 2), 256, 0, stream>>>(img1, img2, smooth,
                                                                    cand_val, cand_idx, counts);
  rank_partial_kernel<<<dim3(CAP / 256, CAP / 256, 2), 256, 0, stream>>>(cand_val, cand_idx, counts, rank_arr);
  scatter_topk_kernel<<<dim3(CAP / 256, 2), 256, 0, stream>>>(cand_val, cand_idx, counts, rank_arr, sel_val, sel_idx);
  kp_desc_kernel<<<1024, 64, 0, stream>>>(sel_val, sel_idx, smooth, desc, a2, out);
  similarity_tiled_kernel<<<dim3(32, 16), 128, 0, stream>>>(desc, a2, K);
  float* bufs[3] = {cs0, cs1, cs2};
  for (int t = 0; t < 20; ++t) {
    sink_iter_kernel<<<65, SB, 0, stream>>>(
        K, bufs[(t + 2) % 3], bufs[t % 3], bufs[(t + 1) % 3], a_vec);
  }
  // final colsum lives in bufs[19 % 3] = cs1
  probs_kernel<<<(513 * 513 + 255) / 256, 256, 0, stream>>>(K, a_vec, bufs[19 % 3], out + 2048);
}

// Round 8
// 204.019 us; speedup vs baseline: 1.1932x; 1.0002x over previous
//
#include <hip/hip_runtime.h>
#include <math.h>

#define IMH 480
#define IMW 640
#define HW (IMH*IMW)
#define KPT 512
#define DESC 256
#define CAP 12288
#define NMSR 3

// ---------------------------------------------------------------- BAD offsets at COMPILE TIME
// np.random.RandomState(42).uniform(-8,8,(256,4)) -> np.round (half-to-even) -> int.
struct OffsTable { int v[1024]; };

constexpr unsigned mt_temper(unsigned y) {
  y ^= (y >> 11);
  y ^= (y << 7)  & 0x9d2c5680u;
  y ^= (y << 15) & 0xefc60000u;
  y ^= (y >> 18);
  return y;
}

constexpr OffsTable make_offs() {
  OffsTable T{};
  unsigned mt[624]{};
  unsigned s = 42u;
  for (int i = 0; i < 624; ++i) { mt[i] = s; s = 1812433253u * (s ^ (s >> 30)) + (unsigned)i + 1u; }
  int mti = 624;
  unsigned draws[2048]{};
  for (int i = 0; i < 2048; ++i) {
    if (mti >= 624) {
      for (int k = 0; k < 624; ++k) {
        unsigned y = (mt[k] & 0x80000000u) | (mt[(k + 1) % 624] & 0x7fffffffu);
        unsigned v = mt[(k + 397) % 624] ^ (y >> 1);
        if (y & 1u) v ^= 0x9908b0dfu;
        mt[k] = v;
      }
      mti = 0;
    }
    draws[i] = mt_temper(mt[mti++]);
  }
  for (int i = 0; i < 1024; ++i) {
    unsigned a = draws[2 * i] >> 5, b = draws[2 * i + 1] >> 6;
    double r = ((double)a * 67108864.0 + (double)b) / 9007199254740992.0;
    double val = -8.0 + 16.0 * r;
    double f = (double)(long long)val;
    if (val < f) f -= 1.0;                 // floor
    double diff = val - f;
    double rounded;
    if (diff > 0.5) rounded = f + 1.0;
    else if (diff < 0.5) rounded = f;
    else { long long fi = (long long)f; rounded = (fi % 2 == 0) ? f : f + 1.0; }  // half->even
    T.v[i] = (int)rounded;
  }
  return T;
}

__constant__ OffsTable OFFS_TAB = make_offs();

// ---------------------------------------------------------------- init
// Pre-writes defaults for unclaimed keypoint slots (kp=-1, desc=0, a2=0):
// the direct-rank kp_desc only touches winners (rank < 512).
__global__ void init_misc_kernel(int* __restrict__ counts,
                                 float* __restrict__ cs0, float* __restrict__ cs1,
                                 float* __restrict__ cs2,
                                 int* __restrict__ rank_arr, float* __restrict__ K,
                                 float* __restrict__ desc, float* __restrict__ a2,
                                 float* __restrict__ out) {
  int t = blockIdx.x * blockDim.x + threadIdx.x;
  if (t < 2) counts[t] = 0;
  if (t < 513) {
    // triple-buffer colsum rotation: iteration t reads cs[(t+2)%3], atomically
    // accumulates cs[t%3], zeros cs[(t+1)%3]. Seed the first read buffer (cs2)
    // with nu so b0 = nu/cs2 = 1 (v=0 initial), zero the first write buffer.
    cs0[t] = 0.f;
    cs1[t] = 0.f;
    cs2[t] = (t == KPT) ? 0.5f : (1.0f / 1024.0f);
    // dustbin row/col of the linear-domain kernel matrix: exp(UNUSED/EPS)=exp(1)
    float e = expf(1.0f);
    K[(size_t)KPT * 513 + t] = e;
    K[(size_t)t * 513 + KPT] = e;
  }
  if (t < 2 * KPT) a2[t] = 0.f;
  if (t < 4 * KPT) out[t] = -1.f;          // kp defaults (both images)
  for (int i = t; i < 2 * CAP; i += 16384) rank_arr[i] = 0;
  // desc zero: 2*KPT*DESC = 262144 floats = 65536 float4
  float4* d4 = (float4*)desc;
  for (int i = t; i < 65536; i += 16384) d4[i] = make_float4(0.f, 0.f, 0.f, 0.f);
}

// ---------------------------------------------------------------- fused detector + NMS
// FTH=16: score stencil computes (FTH+6)x(FTW+6) to emit FTHxFTW; halo
// redundancy 1.50x (vs 1.91x at FTH=8, proven -3.5 us in R7). Per-block
// maxima <= 85 (4x4 packing bound for radius-3 NMS) stays under the
// 128-slot cap.
#define FTW 64
#define FTH 16
__global__ void det_nms_kernel(const float* __restrict__ img0, const float* __restrict__ img1,
                               float* __restrict__ smooth,
                               float* __restrict__ cand_val, int* __restrict__ cand_idx,
                               int* __restrict__ counts) {
  const int b = blockIdx.z;
  const int x0 = blockIdx.x * FTW;
  const int y0 = blockIdx.y * FTH;
  const float* __restrict__ img = b ? img1 : img0;
  __shared__ float im[(FTH + 10) * (FTW + 10)];   // 26 x 74 image stage (0 OOB)
  __shared__ float scs[(FTH + 6) * (FTW + 6)];    // 22 x 70 scores (-inf OOB)
  __shared__ float hm[(FTH + 6) * FTW];           // 22 x 64 horizontal 7-max
  __shared__ float lval[128];
  __shared__ int lidx[128];
  __shared__ int lcnt, gbase;
  const int tid = threadIdx.x;
  if (tid == 0) lcnt = 0;
  for (int i = tid; i < (FTH + 10) * 74; i += 256) {
    int ly = i / 74, lx = i - ly * 74;
    int gy = y0 + ly - 5, gx = x0 + lx - 5;
    im[i] = (gy >= 0 && gy < IMH && gx >= 0 && gx < IMW) ? img[gy * IMW + gx] : 0.f;
  }
  __syncthreads();
  for (int i = tid; i < (FTH + 6) * 70; i += 256) {
    int ly = i / 70, lx = i - ly * 70;
    int gy = y0 + ly - 3, gx = x0 + lx - 3;
    float sc;
    if (gy < 0 || gy >= IMH || gx < 0 || gx >= IMW) {
      sc = -INFINITY;                 // reference NMS pads with -inf
    } else {
      float a[5][5];
      #pragma unroll
      for (int ii = 0; ii < 5; ++ii)
        #pragma unroll
        for (int jj = 0; jj < 5; ++jj)
          a[ii][jj] = im[(ly + ii) * 74 + lx + jj];
      float sm = 0.f;
      #pragma unroll
      for (int ii = 0; ii < 5; ++ii)
        #pragma unroll
        for (int jj = 0; jj < 5; ++jj) sm += a[ii][jj];
      if (ly >= 3 && ly < 3 + FTH && lx >= 3 && lx < 3 + FTW)
        smooth[b * HW + gy * IMW + gx] = sm * (1.f / 25.f);
      float sxx = 0.f, syy = 0.f, sxy = 0.f;
      #pragma unroll
      for (int cy = -1; cy <= 1; ++cy) {
        #pragma unroll
        for (int cx = -1; cx <= 1; ++cx) {
          int yy = gy + cy, xx = gx + cx;
          if (yy < 0 || yy >= IMH || xx < 0 || xx >= IMW) continue;  // zero-pad box conv
          int iu = cy + 2, iv = cx + 2;
          float ix = (a[iu - 1][iv + 1] - a[iu - 1][iv - 1])
                   + 2.f * (a[iu][iv + 1] - a[iu][iv - 1])
                   + (a[iu + 1][iv + 1] - a[iu + 1][iv - 1]);
          float iy = (a[iu + 1][iv - 1] + 2.f * a[iu + 1][iv] + a[iu + 1][iv + 1])
                   - (a[iu - 1][iv - 1] + 2.f * a[iu - 1][iv] + a[iu - 1][iv + 1]);
          sxx += ix * ix; syy += iy * iy; sxy += ix * iy;
        }
      }
      sxx *= (1.f / 9.f); syy *= (1.f / 9.f); sxy *= (1.f / 9.f);
      float half_tr = 0.5f * (sxx + syy);
      float hd = 0.5f * (sxx - syy);
      sc = half_tr - sqrtf(hd * hd + sxy * sxy + 1e-12f);
    }
    scs[i] = sc;
  }
  __syncthreads();
  for (int i = tid; i < (FTH + 6) * 64; i += 256) {
    int ly = i / 64, lx = i - ly * 64;
    const float* r = scs + ly * 70 + lx;
    float m = r[0];
    #pragma unroll
    for (int d = 1; d < 7; ++d) m = fmaxf(m, r[d]);
    hm[i] = m;
  }
  __syncthreads();
  for (int i = tid; i < FTH * FTW; i += 256) {
    int ly = i >> 6, lx = i & 63;
    float s = scs[(ly + 3) * 70 + lx + 3];
    if (s > 0.f) {
      float m = hm[ly * 64 + lx];
      #pragma unroll
      for (int d = 1; d < 7; ++d) m = fmaxf(m, hm[(ly + d) * 64 + lx]);
      if (s >= m - 1e-7f) {
        int slot = atomicAdd(&lcnt, 1);
        if (slot < 128) { lval[slot] = s; lidx[slot] = (y0 + ly) * IMW + (x0 + lx); }
      }
    }
  }
  __syncthreads();
  if (tid == 0) gbase = atomicAdd(&counts[b], min(lcnt, 128));
  __syncthreads();
  int nc = min(lcnt, 128);
  for (int i = tid; i < nc; i += 256) {
    int slot = gbase + i;
    if (slot < CAP) {
      cand_val[b * CAP + slot] = lval[i];
      cand_idx[b * CAP + slot] = lidx[i];
    }
  }
}

// ---------------------------------------------------------------- top-512: 2D-tiled rank count
// (R6 lesson: the sort+binary-search alternative concentrated the rank into
// ~14 serial-loop blocks -> latency chain, +23 us. This all-pairs version is
// ~5 us of VALU spread over ~1250 blocks — block count IS the resource.)
__global__ void rank_partial_kernel(const float* __restrict__ cand_val,
                                    const int* __restrict__ cand_idx,
                                    const int* __restrict__ counts,
                                    int* __restrict__ rank_arr) {
  int b = blockIdx.z;
  int n = counts[b]; if (n > CAP) n = CAP;
  if ((int)(blockIdx.x * 256) >= n || (int)(blockIdx.y * 256) >= n) return;
  const float* cv = cand_val + b * CAP;
  const int* ci = cand_idx + b * CAP;
  int i = blockIdx.x * 256 + threadIdx.x;
  int j = blockIdx.y * 256 + threadIdx.x;
  __shared__ unsigned long long sk[256];
  sk[threadIdx.x] = (j < n)
      ? (((unsigned long long)__float_as_uint(cv[j]) << 32) | (0xFFFFFFFFu - (unsigned)ci[j]))
      : 0ull;
  __syncthreads();
  if (i >= n) return;
  unsigned long long ki = ((unsigned long long)__float_as_uint(cv[i]) << 32)
                        | (0xFFFFFFFFu - (unsigned)ci[i]);
  int r = 0;
  #pragma unroll 8
  for (int t = 0; t < 256; ++t) r += (sk[t] > ki) ? 1 : 0;
  atomicAdd(&rank_arr[b * CAP + i], r);
}

// ---------------------------------------------------------------- direct-rank kp + BAD desc + L2 norm
// One wave per CANDIDATE (grid 3072x2, 4 waves/block): wave i reads its
// final rank (complete at the dispatch boundary after rank_partial — no
// fence, R5's lesson), exits if rank >= 512, else computes the descriptor
// and writes straight to slot `rank`. Deletes the scatter dispatch and the
// sel_* round trip while KEEPING one dedicated wave per winner (R3's
// lesson: the random gather into smooth is latency-bound; wave count is
// the resource). Loser waves are two loads + exit, latency-overlapped.
__global__ void kp_desc_kernel(const float* __restrict__ cand_val,
                               const int* __restrict__ cand_idx,
                               const int* __restrict__ counts,
                               const int* __restrict__ rank_arr,
                               const float* __restrict__ smooth,
                               float* __restrict__ desc, float* __restrict__ a2_out,
                               float* __restrict__ out) {
  const int b = blockIdx.y;
  int n = counts[b]; if (n > CAP) n = CAP;
  const int wave = threadIdx.x >> 6, lane = threadIdx.x & 63;
  const int i = blockIdx.x * 4 + wave;
  if (i >= n) return;
  const int r = rank_arr[b * CAP + i];
  if (r >= KPT) return;
  const int idx = cand_idx[b * CAP + i];
  const int y = idx / IMW, x = idx - (idx / IMW) * IMW;
  const float* sm = smooth + b * HW;
  float d[4];
  #pragma unroll
  for (int t2 = 0; t2 < 4; ++t2) {
    int pp = (lane << 2) + t2;
    int oy1 = OFFS_TAB.v[4 * pp + 0], ox1 = OFFS_TAB.v[4 * pp + 1];
    int oy2 = OFFS_TAB.v[4 * pp + 2], ox2 = OFFS_TAB.v[4 * pp + 3];
    int ya = min(max(y + oy1, 0), IMH - 1), xa = min(max(x + ox1, 0), IMW - 1);
    int yb = min(max(y + oy2, 0), IMH - 1), xb = min(max(x + ox2, 0), IMW - 1);
    d[t2] = sm[ya * IMW + xa] - sm[yb * IMW + xb];
  }
  float ss = d[0] * d[0] + d[1] * d[1] + d[2] * d[2] + d[3] * d[3];
  #pragma unroll
  for (int off = 32; off; off >>= 1) ss += __shfl_down(ss, off);
  ss = __shfl(ss, 0);
  float scale = 1.f / (sqrtf(ss) + 1e-8f);
  float* dd = desc + (size_t)(b * KPT + r) * DESC;
  #pragma unroll
  for (int t2 = 0; t2 < 4; ++t2) dd[(lane << 2) + t2] = d[t2] * scale;
  if (lane == 0) {
    a2_out[b * KPT + r] = ss * scale * scale;
    float* kp = out + b * (2 * KPT) + r * 2;
    kp[0] = (float)y;
    kp[1] = (float)x;
  }
}

// ---------------------------------------------------------------- similarity: LDS-tiled GEMM, 512 blocks
// 32x16 tile/block, 128 threads, 2x2 regs/thread. Grid 32x16 = 512 blocks ->
// 2 blocks/CU co-resident. CK=128: 2 chunks, half the barriers. Accumulation
// strictly k-ascending. Kt is GONE: the fused sinkhorn reads K rows for the
// column reduction (coalesced), so the transposed copy is dead weight.
#define CK 128
#define APITCH 34
#define BPITCH 18
__global__ __launch_bounds__(128) void similarity_tiled_kernel(
    const float* __restrict__ desc, const float* __restrict__ a2,
    float* __restrict__ K) {
  __shared__ float As[CK * APITCH];   // [k][row], 32 rows
  __shared__ float Bs[CK * BPITCH];   // [k][col], 16 cols
  __shared__ float T[32 * 17];        // output tile for coalesced writes
  const int tid = threadIdx.x;
  const int tx = tid & 7;         // col-pair index (16 cols)
  const int ty = tid >> 3;        // row-pair index (32 rows)
  const int row0 = blockIdx.y * 32;
  const int col0 = blockIdx.x * 16;
  float acc[2][2] = {};
  for (int kc = 0; kc < DESC; kc += CK) {
    for (int i = tid; i < 32 * CK; i += 128) {
      int c = i & (CK - 1), r = i >> 7;   // consecutive lanes -> consecutive c: coalesced
      As[c * APITCH + r] = desc[(size_t)(row0 + r) * DESC + kc + c];
    }
    for (int i = tid; i < 16 * CK; i += 128) {
      int c = i & (CK - 1), r = i >> 7;
      Bs[c * BPITCH + r] = desc[(size_t)(KPT + col0 + r) * DESC + kc + c];
    }
    __syncthreads();
    #pragma unroll 16
    for (int kk = 0; kk < CK; ++kk) {
      const float2 av = *(const float2*)&As[kk * APITCH + ty * 2];
      const float2 bv = *(const float2*)&Bs[kk * BPITCH + tx * 2];
      acc[0][0] += av.x * bv.x; acc[0][1] += av.x * bv.y;
      acc[1][0] += av.y * bv.x; acc[1][1] += av.y * bv.y;
    }
    __syncthreads();
  }
  float a2k[2], b2l[2];
  #pragma unroll
  for (int i = 0; i < 2; ++i) {
    a2k[i] = a2[row0 + ty * 2 + i];
    b2l[i] = a2[KPT + col0 + tx * 2 + i];
  }
  #pragma unroll
  for (int i = 0; i < 2; ++i)
    #pragma unroll
    for (int j = 0; j < 2; ++j) {
      float sq = fmaxf(a2k[i] + b2l[j] - 2.f * acc[i][j], 0.f);
      T[(ty * 2 + i) * 17 + tx * 2 + j] = expf(-sqrtf(sq + 1e-12f));
    }
  __syncthreads();
  for (int i = tid; i < 512; i += 128) {
    int r = i >> 4, c = i & 15;
    K[(size_t)(row0 + r) * 513 + col0 + c] = T[r * 17 + c];
  }
}

// ---------------------------------------------------------------- sinkhorn, linear domain, FUSED iteration
// One dispatch per full iteration: a = mu / (K b); colsum = K^T a.
// R4-proven configuration: SROWS=8 / SB=512 / 65 blocks, K-tile staged into
// LDS once (coalesced, issued at kernel entry, overlapping the cs_prev load
// + b compute); both phases read the tile from LDS. One row dot per wave.
// (R2/R5 variants with taller blocks or serial dots regressed: these
// dispatches are latency-bound, per-block critical path is the metric.)
// Triple-buffer rotation: read cs[(t+2)%3], accumulate cs[t%3], zero
// cs[(t+1)%3] — the zeroed buffer is never touched by this dispatch's
// readers/writers; dispatch boundary orders it for iteration t+1.
#define SB 512
#define SROWS 8
__global__ __launch_bounds__(SB) void sink_iter_kernel(
    const float* __restrict__ Kmat, const float* __restrict__ cs_prev,
    float* __restrict__ cs_next, float* __restrict__ cs_zero,
    float* __restrict__ a_out) {
  __shared__ float tile[SROWS * 513];
  __shared__ float b_lds[513];
  __shared__ float a_lds[SROWS];
  const int tid = threadIdx.x;
  const int k0 = blockIdx.x * SROWS;
  const int nrows = min(SROWS, 513 - k0);      // last block (k0=512) has 1 row
  // K-tile stage: contiguous rows k0..k0+nrows-1, fully coalesced, issued first
  for (int i = tid; i < nrows * 513; i += SB)
    tile[i] = Kmat[(size_t)k0 * 513 + i];
  for (int l = tid; l < 513; l += SB) {
    float nu = (l == KPT) ? 0.5f : (1.0f / 1024.0f);
    b_lds[l] = nu / cs_prev[l];
  }
  if (blockIdx.x == 0) {
    for (int l = tid; l < 513; l += SB) cs_zero[l] = 0.f;
  }
  __syncthreads();
  // a-update: wave w owns row k0+w; same lane mapping + butterfly as R1/R4
  const int w = tid >> 6, lane = tid & 63;
  const int k = k0 + w;
  if (w < nrows) {
    const float* row = tile + w * 513;
    float s = 0.f;
    for (int i = lane; i < 513; i += 64) s += row[i] * b_lds[i];
    #pragma unroll
    for (int off = 32; off; off >>= 1) s += __shfl_xor(s, off);
    if (lane == 0) {
      float mu = (k == KPT) ? 0.5f : (1.0f / 1024.0f);
      float av = mu / s;
      a_lds[w] = av;
      a_out[k] = av;
    }
  }
  __syncthreads();
  // column partial from the LDS tile, w2 ascending (same order as R1/R4)
  for (int l = tid; l < 513; l += SB) {
    float p = 0.f;
    for (int w2 = 0; w2 < nrows; ++w2)
      p += a_lds[w2] * tile[w2 * 513 + l];
    atomicAdd(&cs_next[l], p);
  }
}

__global__ void probs_kernel(const float* __restrict__ K, const float* __restrict__ a,
                             const float* __restrict__ cs, float* __restrict__ out) {
  int t = blockIdx.x * blockDim.x + threadIdx.x;
  if (t >= 513 * 513) return;
  int k = t / 513;
  int l = t - k * 513;
  float nu = (l == KPT) ? 0.5f : (1.0f / 1024.0f);
  float b = nu / cs[l];
  out[t] = K[t] * (a[k] * 1024.f) * b;
}

// ---------------------------------------------------------------- launch
extern "C" void kernel_launch(void* const* d_in, const int* in_sizes, int n_in,
                              void* d_out, int out_size, void* d_ws, size_t ws_size,
                              hipStream_t stream) {
  const float* img1 = (const float*)d_in[0];
  const float* img2 = (const float*)d_in[1];
  float* out = (float*)d_out;

  char* p = (char*)d_ws;
  auto alloc = [&](size_t bytes) { char* r = p; p += (bytes + 255) & ~(size_t)255; return r; };
  int*   counts   = (int*)alloc(2 * 4);
  float* a_vec    = (float*)alloc(513 * 4);
  float* cs0      = (float*)alloc(513 * 4);
  float* cs1      = (float*)alloc(513 * 4);
  float* cs2      = (float*)alloc(513 * 4);
  float* a2       = (float*)alloc(2 * KPT * 4);
  float* smooth   = (float*)alloc((size_t)2 * HW * 4);
  float* cand_val = (float*)alloc((size_t)2 * CAP * 4);
  int*   cand_idx = (int*)alloc((size_t)2 * CAP * 4);
  int*   rank_arr = (int*)alloc((size_t)2 * CAP * 4);
  float* desc     = (float*)alloc((size_t)2 * KPT * DESC * 4);
  float* K        = (float*)alloc((size_t)513 * 513 * 4);

  init_misc_kernel<<<64, 256, 0, stream>>>(counts, cs0, cs1, cs2, rank_arr, K, desc, a2, out);
  det_nms_kernel<<<dim3(IMW / FTW, IMH / FTH, 2), 256, 0, stream>>>(img1, img2, smooth,
                                                                    cand_val, cand_idx, counts);
  rank_partial_kernel<<<dim3(CAP / 256, CAP / 256, 2), 256, 0, stream>>>(cand_val, cand_idx, counts, rank_arr);
  kp_desc_kernel<<<dim3(CAP / 4, 2), 256, 0, stream>>>(cand_val, cand_idx, counts, rank_arr,
                                                       smooth, desc, a2, out);
  similarity_tiled_kernel<<<dim3(32, 16), 128, 0, stream>>>(desc, a2, K);
  float* bufs[3] = {cs0, cs1, cs2};
  for (int t = 0; t < 20; ++t) {
    sink_iter_kernel<<<65, SB, 0, stream>>>(
        K, bufs[(t + 2) % 3], bufs[t % 3], bufs[(t + 1) % 3], a_vec);
  }
  // final colsum lives in bufs[19 % 3] = cs1
  probs_kernel<<<(513 * 513 + 255) / 256, 256, 0, stream>>>(K, a_vec, bufs[19 % 3], out + 2048);
}